// Round 3
// baseline (96.637 us; speedup 1.0000x reference)
//
#include <hip/hip_runtime.h>
#include <hip/hip_bf16.h>

// Problem constants
#define CCH   256        // channels C
#define NG    16         // groups
#define GCN   16         // group channels
#define CRD   64         // reduced channels C/R
#define HH    56
#define WWD   56
#define HWP   3136       // 56*56
#define BB    8
#define NPIX  25088      // B*H*W
#define PADW  62         // 56 + 2*3
#define PADHW 3844       // 62*62
#define K2    49
#define O2N   784        // K2 * NG
#define EPSV  1e-5f

typedef unsigned short ushort_t;
typedef __attribute__((ext_vector_type(8))) short bf16x8;
typedef __attribute__((ext_vector_type(4))) float f32x4;

// workspace layout (float units)
#define XP_OFF   0
#define XP_SZ    7872512                  // 8*256*3844 floats
#define XW_OFF   7872512                  // x_t: 25088*256 shorts; wgt: 25088*784 shorts
#define YT_OFF   17707008                 // XW_OFF + 784*25088/2
#define W1B_OFF  18509824                 // YT_OFF + 25088*64/2
#define W2B_OFF  18518016                 // + 16384/2
#define BNS_OFF  18543104                 // + 50176/2
#define BNT_OFF  18543168                 // + 64
// end = 18543232 floats = 74.2 MB

__device__ __forceinline__ ushort_t f2bf(float f) {
    unsigned u = __builtin_bit_cast(unsigned, f);
    return (ushort_t)((u + 0x7FFFu + ((u >> 16) & 1u)) >> 16);   // RNE
}
__device__ __forceinline__ float bf2f(ushort_t s) {
    return __builtin_bit_cast(float, (unsigned)s << 16);
}

// ---------------------------------------------------------------------------
// prep: zero-pad x into xp; W1,W2 -> bf16; fold BN+bias into scale/shift
// ---------------------------------------------------------------------------
__global__ __launch_bounds__(256) void prep_kernel(const float* __restrict__ x,
                                                   const float* __restrict__ W1,
                                                   const float* __restrict__ b1,
                                                   const float* __restrict__ gamma,
                                                   const float* __restrict__ beta,
                                                   const float* __restrict__ mean,
                                                   const float* __restrict__ var,
                                                   const float* __restrict__ W2,
                                                   float* __restrict__ ws) {
    int gid0 = blockIdx.x * 256 + threadIdx.x;
    int stride = gridDim.x * 256;
    float* xp = ws + XP_OFF;
    for (int e = gid0; e < XP_SZ; e += stride) {
        int col = e % PADW;
        int row = (e / PADW) % PADW;
        int bc  = e / PADHW;
        int sr = row - 3, sc = col - 3;
        float v = 0.f;
        if ((unsigned)sr < (unsigned)HH && (unsigned)sc < (unsigned)WWD)
            v = x[bc * HWP + sr * WWD + sc];
        xp[e] = v;
    }
    ushort_t* w1b = (ushort_t*)(ws + W1B_OFF);
    if (gid0 < CRD * CCH) w1b[gid0] = f2bf(W1[gid0]);          // [o][c] row-major
    ushort_t* w2b = (ushort_t*)(ws + W2B_OFF);
    if (gid0 < O2N * CRD) w2b[gid0] = f2bf(W2[gid0]);          // [o2][c] row-major
    if (gid0 < CRD) {
        float s = gamma[gid0] * rsqrtf(var[gid0] + EPSV);
        ws[BNS_OFF + gid0] = s;
        ws[BNT_OFF + gid0] = (b1[gid0] - mean[gid0]) * s + beta[gid0];
    }
}

// ---------------------------------------------------------------------------
// pack_x: transpose x (B,C,H,W) -> x_t[pix][256] bf16 via LDS (64 hw x 256 c tile)
// ---------------------------------------------------------------------------
__global__ __launch_bounds__(256) void pack_x(const float* __restrict__ x,
                                              float* __restrict__ ws) {
    __shared__ ushort_t st[64 * 270];      // pad 256->270 shorts (odd-word row stride)
    int tid = threadIdx.x;
    int b = blockIdx.y, hw0 = blockIdx.x * 64;
    int lane = tid & 63, c4 = tid >> 6;
    const float* xb = x + (b * CCH) * HWP + hw0 + lane;
#pragma unroll 8
    for (int i = 0; i < 64; ++i) {
        int c = i * 4 + c4;
        st[lane * 270 + c] = f2bf(xb[c * HWP]);
    }
    __syncthreads();
    const unsigned* stu = (const unsigned*)st;           // row stride 135 words
    unsigned* xtu = (unsigned*)(ws + XW_OFF);            // x_t rows: 128 words
    int rowg = b * HWP + hw0;
#pragma unroll
    for (int k = 0; k < 32; ++k) {
        int idx = k * 256 + tid;
        int row = idx >> 7, c2 = idx & 127;
        xtu[(rowg + row) * 128 + c2] = stu[row * 135 + c2];
    }
}

// ---------------------------------------------------------------------------
// conv1 (MFMA bf16): y_t[pix][64] = relu(bns[o]*(x_t @ W1^T)[o][pix] + bnt[o])
// ---------------------------------------------------------------------------
__global__ __launch_bounds__(256) void conv1_mfma(float* __restrict__ ws) {
    const ushort_t* xt  = (const ushort_t*)(ws + XW_OFF);
    const ushort_t* w1b = (const ushort_t*)(ws + W1B_OFF);
    const float* bns = ws + BNS_OFF;
    const float* bnt = ws + BNT_OFF;
    ushort_t* yt = (ushort_t*)(ws + YT_OFF);

    int tid = threadIdx.x, lane = tid & 63, wv = tid >> 6;
    int lr = lane & 15, lg = lane >> 4;
    int ot = blockIdx.x;                                  // 0..3
    int pixbase = blockIdx.y * 128 + wv * 32;

    const bf16x8* ap = (const bf16x8*)(w1b + (ot * 16 + lr) * CCH + lg * 8);
    bf16x8 a[8];
#pragma unroll
    for (int ks = 0; ks < 8; ++ks) a[ks] = ap[ks * 4];    // kstep = 32 shorts = 4 units

    f32x4 acc[2] = {{0.f,0.f,0.f,0.f}, {0.f,0.f,0.f,0.f}};
#pragma unroll
    for (int f = 0; f < 2; ++f) {
        const bf16x8* bp = (const bf16x8*)(xt + (pixbase + f * 16 + lr) * CCH + lg * 8);
#pragma unroll
        for (int ks = 0; ks < 8; ++ks)
            acc[f] = __builtin_amdgcn_mfma_f32_16x16x32_bf16(a[ks], bp[ks * 4], acc[f], 0, 0, 0);
    }

    int o0 = ot * 16 + lg * 4;
    float4 s4 = *(const float4*)(bns + o0);
    float4 t4 = *(const float4*)(bnt + o0);
#pragma unroll
    for (int f = 0; f < 2; ++f) {
        int pix = pixbase + f * 16 + lr;
        union { ushort_t u[4]; uint2 v; } pk;
        pk.u[0] = f2bf(fmaxf(acc[f][0] * s4.x + t4.x, 0.f));
        pk.u[1] = f2bf(fmaxf(acc[f][1] * s4.y + t4.y, 0.f));
        pk.u[2] = f2bf(fmaxf(acc[f][2] * s4.z + t4.z, 0.f));
        pk.u[3] = f2bf(fmaxf(acc[f][3] * s4.w + t4.w, 0.f));
        *(uint2*)(yt + pix * CRD + o0) = pk.v;
    }
}

// ---------------------------------------------------------------------------
// conv2 (MFMA bf16): wgt[o2][pix] bf16 = (W2 @ y)[o2][pix] + b2[o2]
// ---------------------------------------------------------------------------
__global__ __launch_bounds__(256) void conv2_mfma(const float* __restrict__ b2,
                                                  float* __restrict__ ws) {
    const ushort_t* yt  = (const ushort_t*)(ws + YT_OFF);
    const ushort_t* w2b = (const ushort_t*)(ws + W2B_OFF);
    ushort_t* wgt = (ushort_t*)(ws + XW_OFF);             // overlays dead x_t

    int tid = threadIdx.x, lane = tid & 63, wv = tid >> 6;
    int lr = lane & 15, lg = lane >> 4;
    int o2base = blockIdx.y * 16;
    int pixbase = blockIdx.x * 256 + wv * 64;

    const bf16x8* ap = (const bf16x8*)(w2b + (o2base + lr) * CRD + lg * 8);
    bf16x8 a0 = ap[0], a1 = ap[4];

    f32x4 acc[4] = {{0.f,0.f,0.f,0.f},{0.f,0.f,0.f,0.f},{0.f,0.f,0.f,0.f},{0.f,0.f,0.f,0.f}};
#pragma unroll
    for (int f = 0; f < 4; ++f) {
        const bf16x8* bp = (const bf16x8*)(yt + (pixbase + f * 16 + lr) * CRD + lg * 8);
        acc[f] = __builtin_amdgcn_mfma_f32_16x16x32_bf16(a0, bp[0], acc[f], 0, 0, 0);
        acc[f] = __builtin_amdgcn_mfma_f32_16x16x32_bf16(a1, bp[4], acc[f], 0, 0, 0);
    }

    int r0 = lg * 4;
    float4 b2v = *(const float4*)(b2 + o2base + r0);
    float b2a[4] = {b2v.x, b2v.y, b2v.z, b2v.w};
#pragma unroll
    for (int f = 0; f < 4; ++f) {
        unsigned pix = (unsigned)(pixbase + f * 16 + lr);
        unsigned b  = pix / 3136u;
        unsigned hw = pix - b * 3136u;
        ushort_t* wp = wgt + ((b * O2N + o2base + r0) * HWP + hw);
#pragma unroll
        for (int j = 0; j < 4; ++j)
            wp[j * HWP] = f2bf(acc[f][j] + b2a[j]);
    }
}

// ---------------------------------------------------------------------------
// involution: out[b, g*16+ch, h, w] = sum_k xp[b, ch, h+ki, w+kj] * wgt[b,g,k,h,w]
// wgt tile kept bf16 in LDS (21.9 KB -> 7 blocks/CU, 28 waves/CU).
// ---------------------------------------------------------------------------
__global__ __launch_bounds__(256, 7) void invol_kernel(const float* __restrict__ ws,
                                                       const ushort_t* __restrict__ wgt,
                                                       float* __restrict__ out) {
    __shared__ ushort_t wl[K2 * 4 * WWD];   // 49*4*56 bf16 = 21952 B
    int h0 = blockIdx.x * 4;
    int g  = blockIdx.y;
    int b  = blockIdx.z;
    int tid = threadIdx.x;

    // stage wgt tile: per k, 4 rows x 56 = 224 contiguous bf16 = 112 words
    const unsigned* wg = (const unsigned*)(wgt + (b * O2N + g * K2) * HWP + h0 * WWD);
    unsigned* wlu = (unsigned*)wl;
    for (int i = tid; i < K2 * 112; i += 256) {
        int k = i / 112, rem = i - k * 112;
        wlu[i] = wg[k * (HWP / 2) + rem];
    }
    __syncthreads();

    int w  = tid & 63;
    int cq = tid >> 6;                 // channel quad 0..3
    if (w < WWD) {
        const float* xpb = ws + XP_OFF + (b * CCH + g * GCN + cq * 4) * PADHW + h0 * PADW + w;

        float acc[4][4];               // [c][r]
#pragma unroll
        for (int c = 0; c < 4; ++c)
#pragma unroll
            for (int r = 0; r < 4; ++r) acc[c][r] = 0.f;

#pragma unroll
        for (int xr = 0; xr < 10; ++xr) {
            float xv[4][8];
#pragma unroll
            for (int c = 0; c < 4; ++c)
                __builtin_memcpy(&xv[c][0], xpb + c * PADHW + xr * PADW, 32);
#pragma unroll
            for (int ki = 0; ki < 7; ++ki) {
                int r = xr - ki;       // compile-time after full unroll
                if (r >= 0 && r < 4) {
#pragma unroll
                    for (int dj = 0; dj < 7; ++dj) {
                        float wv = bf2f(wl[((ki * 7 + dj) * 4 + r) * WWD + w]);
#pragma unroll
                        for (int c = 0; c < 4; ++c)
                            acc[c][r] = fmaf(xv[c][dj], wv, acc[c][r]);
                    }
                }
            }
        }

#pragma unroll
        for (int c = 0; c < 4; ++c)
#pragma unroll
            for (int r = 0; r < 4; ++r)
                out[(b * CCH + g * GCN + cq * 4 + c) * HWP + (h0 + r) * WWD + w] = acc[c][r];
    }
}

// ---------------------------------------------------------------------------
extern "C" void kernel_launch(void* const* d_in, const int* in_sizes, int n_in,
                              void* d_out, int out_size, void* d_ws, size_t ws_size,
                              hipStream_t stream) {
    const float* x     = (const float*)d_in[0];
    const float* W1    = (const float*)d_in[1];
    const float* b1    = (const float*)d_in[2];
    const float* gamma = (const float*)d_in[3];
    const float* beta  = (const float*)d_in[4];
    const float* mean  = (const float*)d_in[5];
    const float* var   = (const float*)d_in[6];
    const float* W2    = (const float*)d_in[7];
    const float* b2    = (const float*)d_in[8];

    float* ws  = (float*)d_ws;
    float* out = (float*)d_out;

    prep_kernel<<<4096, 256, 0, stream>>>(x, W1, b1, gamma, beta, mean, var, W2, ws);
    pack_x<<<dim3(HWP / 64, BB), 256, 0, stream>>>(x, ws);
    conv1_mfma<<<dim3(4, NPIX / 128), 256, 0, stream>>>(ws);
    conv2_mfma<<<dim3(NPIX / 256, K2), 256, 0, stream>>>(b2, ws);
    invol_kernel<<<dim3(HH / 4, NG, BB), 256, 0, stream>>>(
        ws, (const ushort_t*)(ws + XW_OFF), out);
}

// Round 4
// 72.583 us; speedup vs baseline: 1.3314x; 1.3314x over previous
//
#include <hip/hip_runtime.h>
#include <hip/hip_bf16.h>

// Problem constants
#define CCH   256        // channels C
#define NG    16         // groups
#define GCN   16         // group channels
#define CRD   64         // reduced channels C/R
#define HH    56
#define WWD   56
#define HWP   3136       // 56*56
#define BB    8
#define NPIX  25088      // B*H*W
#define PADW  62         // 56 + 2*3
#define PADHW 3844       // 62*62
#define K2    49
#define O2N   784        // K2 * NG
#define EPSV  1e-5f

typedef unsigned short ushort_t;
typedef __attribute__((ext_vector_type(8))) short bf16x8;
typedef __attribute__((ext_vector_type(4))) float f32x4;

// workspace layout (float units)
#define XP_OFF   0                         // fp32 padded x: 8*256*3844
#define XP_SZ    7872512
#define XT_OFF   7872512                   // x_t bf16 [pix][256]: 6,422,528 shorts
#define YT_OFF   11083776                  // y_t bf16 [pix][64]: 1,605,632 shorts
#define W1B_OFF  11886592                  // W1 bf16 [64][256]: 16384 shorts
#define W2B_OFF  11894784                  // W2 bf16 padded [800][64]: 51200 shorts
#define B2P_OFF  11920384                  // b2 padded: 800 floats
#define BNS_OFF  11921184                  // 64
#define BNT_OFF  11921248                  // 64
// end = 11,921,312 floats = 47.7 MB

__device__ __forceinline__ ushort_t f2bf(float f) {
    unsigned u = __builtin_bit_cast(unsigned, f);
    return (ushort_t)((u + 0x7FFFu + ((u >> 16) & 1u)) >> 16);   // RNE
}

// ---------------------------------------------------------------------------
// prep: zero xp; W1,W2(bf16, W2 padded to 800 rows); b2 padded; BN fold
// ---------------------------------------------------------------------------
__global__ __launch_bounds__(256) void prep_kernel(const float* __restrict__ W1,
                                                   const float* __restrict__ b1,
                                                   const float* __restrict__ gamma,
                                                   const float* __restrict__ beta,
                                                   const float* __restrict__ mean,
                                                   const float* __restrict__ var,
                                                   const float* __restrict__ W2,
                                                   const float* __restrict__ b2,
                                                   float* __restrict__ ws) {
    int gid = blockIdx.x * 256 + threadIdx.x;
    int stride = gridDim.x * 256;
    uint4 z = {0u, 0u, 0u, 0u};
    uint4* xpv = (uint4*)(ws + XP_OFF);
    for (int e = gid; e < XP_SZ / 4; e += stride) xpv[e] = z;

    ushort_t* w1b = (ushort_t*)(ws + W1B_OFF);
    if (gid < CRD * CCH) w1b[gid] = f2bf(W1[gid]);               // [o][c]
    ushort_t* w2b = (ushort_t*)(ws + W2B_OFF);
    if (gid < 800 * CRD) w2b[gid] = (gid < O2N * CRD) ? f2bf(W2[gid]) : (ushort_t)0;
    if (gid < 800) ws[B2P_OFF + gid] = (gid < O2N) ? b2[gid] : 0.f;
    if (gid < CRD) {
        float s = gamma[gid] * rsqrtf(var[gid] + EPSV);
        ws[BNS_OFF + gid] = s;
        ws[BNT_OFF + gid] = (b1[gid] - mean[gid]) * s + beta[gid];
    }
}

// ---------------------------------------------------------------------------
// pack_x: read x ONCE -> x_t[pix][256] bf16 (LDS transpose) + xp fp32 interior
// ---------------------------------------------------------------------------
__global__ __launch_bounds__(256) void pack_x(const float* __restrict__ x,
                                              float* __restrict__ ws) {
    __shared__ ushort_t st[64 * 270];      // pad 256->270 shorts (odd-word row stride)
    int tid = threadIdx.x;
    int b = blockIdx.y, hw0 = blockIdx.x * 64;
    int lane = tid & 63, c4 = tid >> 6;
    int hw = hw0 + lane;
    int h = hw / WWD, w = hw - h * WWD;
    const float* xb = x + (b * CCH) * HWP + hw;
    float* xpd = ws + XP_OFF + (b * CCH) * PADHW + (h + 3) * PADW + (w + 3);
#pragma unroll 8
    for (int i = 0; i < 64; ++i) {
        int c = i * 4 + c4;
        float v = xb[c * HWP];
        st[lane * 270 + c] = f2bf(v);
        xpd[c * PADHW] = v;
    }
    __syncthreads();
    const unsigned* stu = (const unsigned*)st;           // row stride 135 words
    unsigned* xtu = (unsigned*)(ws + XT_OFF);            // x_t rows: 128 words
    int rowg = b * HWP + hw0;
#pragma unroll
    for (int k = 0; k < 32; ++k) {
        int idx = k * 256 + tid;
        int row = idx >> 7, c2 = idx & 127;
        xtu[(rowg + row) * 128 + c2] = stu[row * 135 + c2];
    }
}

// ---------------------------------------------------------------------------
// conv1 (MFMA bf16): y_t[pix][64] = relu(bns[o]*(x_t @ W1^T)[o][pix] + bnt[o])
// ---------------------------------------------------------------------------
__global__ __launch_bounds__(256) void conv1_mfma(float* __restrict__ ws) {
    const ushort_t* xt  = (const ushort_t*)(ws + XT_OFF);
    const ushort_t* w1b = (const ushort_t*)(ws + W1B_OFF);
    const float* bns = ws + BNS_OFF;
    const float* bnt = ws + BNT_OFF;
    ushort_t* yt = (ushort_t*)(ws + YT_OFF);

    int tid = threadIdx.x, lane = tid & 63, wv = tid >> 6;
    int lr = lane & 15, lg = lane >> 4;
    int ot = blockIdx.x;                                  // 0..3
    int pixbase = blockIdx.y * 128 + wv * 32;

    const bf16x8* ap = (const bf16x8*)(w1b + (ot * 16 + lr) * CCH + lg * 8);
    bf16x8 a[8];
#pragma unroll
    for (int ks = 0; ks < 8; ++ks) a[ks] = ap[ks * 4];

    f32x4 acc[2] = {{0.f,0.f,0.f,0.f}, {0.f,0.f,0.f,0.f}};
#pragma unroll
    for (int f = 0; f < 2; ++f) {
        const bf16x8* bp = (const bf16x8*)(xt + (pixbase + f * 16 + lr) * CCH + lg * 8);
#pragma unroll
        for (int ks = 0; ks < 8; ++ks)
            acc[f] = __builtin_amdgcn_mfma_f32_16x16x32_bf16(a[ks], bp[ks * 4], acc[f], 0, 0, 0);
    }

    int o0 = ot * 16 + lg * 4;
    float4 s4 = *(const float4*)(bns + o0);
    float4 t4 = *(const float4*)(bnt + o0);
#pragma unroll
    for (int f = 0; f < 2; ++f) {
        int pix = pixbase + f * 16 + lr;
        union { ushort_t u[4]; uint2 v; } pk;
        pk.u[0] = f2bf(fmaxf(acc[f][0] * s4.x + t4.x, 0.f));
        pk.u[1] = f2bf(fmaxf(acc[f][1] * s4.y + t4.y, 0.f));
        pk.u[2] = f2bf(fmaxf(acc[f][2] * s4.z + t4.z, 0.f));
        pk.u[3] = f2bf(fmaxf(acc[f][3] * s4.w + t4.w, 0.f));
        *(uint2*)(yt + pix * CRD + o0) = pk.v;
    }
}

// ---------------------------------------------------------------------------
// invol_fused: per block (h0-tile of 4 rows, g, b):
//   A) stage y slice [224 pix][64] bf16 into swizzled LDS
//   B) MFMA: wgt tile (49 o2 x 224 pix) = W2[g-slice] @ y^T + b2; write to
//      LDS as wl[ki][r][w][8] (dj-contiguous, ds_read_b128-friendly)
//   C) involution: out += xp(taps) * wl, 4 ch x 4 rows per thread
// ---------------------------------------------------------------------------
__global__ __launch_bounds__(256, 4) void invol_fused(const float* __restrict__ ws,
                                                      float* __restrict__ out) {
    __shared__ uint4 lds4[1792];           // 28672 B (y stage; reused for wl 25088 B)
    unsigned char* ldsb = (unsigned char*)lds4;

    int h0t = blockIdx.x;                  // 0..13
    int g   = blockIdx.y;
    int b   = blockIdx.z;
    int tid = threadIdx.x, lane = tid & 63, wv = tid >> 6;
    int lr = lane & 15, lg = lane >> 4;
    int pix0 = b * HWP + h0t * 224;

    // ---- Phase A: stage y (224 rows x 128 B), st_16x32-style swizzle
    const uint4* ysrc = (const uint4*)((const ushort_t*)(ws + YT_OFF) + pix0 * CRD);
    for (int i = tid; i < 1792; i += 256) {
        int row = i >> 3;
        unsigned off = (unsigned)(i * 16) ^ (unsigned)((row & 7) << 4);
        *(uint4*)(ldsb + off) = ysrc[i];
    }
    __syncthreads();

    // ---- Phase B: MFMA. wave wv = o2-tile (rows wv*16..+15 of g-slice)
    const ushort_t* w2b = (const ushort_t*)(ws + W2B_OFF);
    const bf16x8* ar = (const bf16x8*)(w2b + (g * K2 + wv * 16 + lr) * CRD);
    bf16x8 a0 = ar[lg], a1 = ar[4 + lg];   // kstep 0 / 1

    f32x4 acc[14];
#pragma unroll
    for (int pt = 0; pt < 14; ++pt) acc[pt] = (f32x4){0.f, 0.f, 0.f, 0.f};
#pragma unroll
    for (int pt = 0; pt < 14; ++pt) {
        int row = pt * 16 + lr;
        unsigned sw = (unsigned)((row & 7) << 4);
        uint4 b0 = *(const uint4*)(ldsb + ((unsigned)(row * 128 + lg * 16) ^ sw));
        uint4 b1 = *(const uint4*)(ldsb + ((unsigned)(row * 128 + 64 + lg * 16) ^ sw));
        acc[pt] = __builtin_amdgcn_mfma_f32_16x16x32_bf16(a0, __builtin_bit_cast(bf16x8, b0), acc[pt], 0, 0, 0);
        acc[pt] = __builtin_amdgcn_mfma_f32_16x16x32_bf16(a1, __builtin_bit_cast(bf16x8, b1), acc[pt], 0, 0, 0);
    }
    __syncthreads();                        // y reads done; reuse LDS for wl

    // ---- Phase B2: wgt -> wl[((ki*4+r)*56+w)*8 + dj]  (16 B per (ki,r,w))
    ushort_t* wl = (ushort_t*)ldsb;
    const float* b2p = ws + B2P_OFF;
    float b2v[4];
#pragma unroll
    for (int j = 0; j < 4; ++j) {
        int k = wv * 16 + lg * 4 + j;
        b2v[j] = b2p[g * K2 + k];           // padded, safe; unused for k>=49
    }
#pragma unroll
    for (int pt = 0; pt < 14; ++pt) {
        int pix = pt * 16 + lr;
        int r = pix / WWD;
        int w = pix - r * WWD;
#pragma unroll
        for (int j = 0; j < 4; ++j) {
            int k = wv * 16 + lg * 4 + j;
            if (k < K2) {
                int ki = k / 7, dj = k - ki * 7;
                wl[(((ki * 4 + r) * WWD + w) << 3) + dj] = f2bf(acc[pt][j] + b2v[j]);
            }
        }
    }
    __syncthreads();

    // ---- Phase C: involution. wave wv = channel quad, lane = w
    int w = lane, cq = wv;
    if (w < WWD) {
        const float* xpb = ws + XP_OFF + (b * CCH + g * GCN + cq * 4) * PADHW
                         + h0t * 4 * PADW + w;
        float acc2[4][4];
#pragma unroll
        for (int c = 0; c < 4; ++c)
#pragma unroll
            for (int r = 0; r < 4; ++r) acc2[c][r] = 0.f;

        const unsigned char* wbase = ldsb + w * 16;
#pragma unroll
        for (int xr = 0; xr < 10; ++xr) {
            float xv[4][8];
#pragma unroll
            for (int c = 0; c < 4; ++c)
                __builtin_memcpy(&xv[c][0], xpb + c * PADHW + xr * PADW, 32);
#pragma unroll
            for (int ki = 0; ki < 7; ++ki) {
                int r = xr - ki;            // compile-time after unroll
                if (r >= 0 && r < 4) {
                    uint4 q = *(const uint4*)(wbase + (ki * 4 + r) * (WWD * 16));
                    unsigned uu[4] = {q.x, q.y, q.z, q.w};
                    float wf[8];
#pragma unroll
                    for (int t = 0; t < 4; ++t) {
                        wf[2 * t]     = __builtin_bit_cast(float, uu[t] << 16);
                        wf[2 * t + 1] = __builtin_bit_cast(float, uu[t] & 0xffff0000u);
                    }
#pragma unroll
                    for (int dj = 0; dj < 7; ++dj)
#pragma unroll
                        for (int c = 0; c < 4; ++c)
                            acc2[c][r] = fmaf(xv[c][dj], wf[dj], acc2[c][r]);
                }
            }
        }

#pragma unroll
        for (int c = 0; c < 4; ++c)
#pragma unroll
            for (int r = 0; r < 4; ++r)
                out[(b * CCH + g * GCN + cq * 4 + c) * HWP + (h0t * 4 + r) * WWD + w]
                    = acc2[c][r];
    }
}

// ---------------------------------------------------------------------------
extern "C" void kernel_launch(void* const* d_in, const int* in_sizes, int n_in,
                              void* d_out, int out_size, void* d_ws, size_t ws_size,
                              hipStream_t stream) {
    const float* x     = (const float*)d_in[0];
    const float* W1    = (const float*)d_in[1];
    const float* b1    = (const float*)d_in[2];
    const float* gamma = (const float*)d_in[3];
    const float* beta  = (const float*)d_in[4];
    const float* mean  = (const float*)d_in[5];
    const float* var   = (const float*)d_in[6];
    const float* W2    = (const float*)d_in[7];
    const float* b2    = (const float*)d_in[8];

    float* ws  = (float*)d_ws;
    float* out = (float*)d_out;

    prep_kernel<<<2048, 256, 0, stream>>>(W1, b1, gamma, beta, mean, var, W2, b2, ws);
    pack_x<<<dim3(HWP / 64, BB), 256, 0, stream>>>(x, ws);
    conv1_mfma<<<dim3(4, NPIX / 128), 256, 0, stream>>>(ws);
    invol_fused<<<dim3(14, NG, BB), 256, 0, stream>>>(ws, out);
}